// Round 1
// 197.170 us; speedup vs baseline: 1.4752x; 1.4752x over previous
//
#include <hip/hip_runtime.h>
#include <hip/hip_bf16.h>
#include <stdint.h>

#define D_MODEL 1024
#define SEQ     2048
#define BATCH   2
#define NH      16
#define HD      64
#define MROWS   (BATCH*SEQ)   // 4096
#define XN      (MROWS*D_MODEL)      // 4194304
#define WN      (D_MODEL*D_MODEL)    // 1048576

typedef __attribute__((ext_vector_type(8))) __bf16 bf16x8;
typedef __attribute__((ext_vector_type(4))) __bf16 bf16x4;
typedef __attribute__((ext_vector_type(4))) float  floatx4;

#define MFMA(a,b,c) __builtin_amdgcn_mfma_f32_16x16x32_bf16((a),(b),(c),0,0,0)

// async global->LDS, 16 B per lane; LDS dest is wave-uniform base + lane*16
__device__ __forceinline__ void g2l16(const void* g, void* l) {
    __builtin_amdgcn_global_load_lds(
        (const __attribute__((address_space(1))) void*)g,
        (__attribute__((address_space(3))) void*)l, 16, 0, 0);
}

// ---------------------------------------------------------------------------
// Kernel 0: convert f32 inputs -> bf16 staging in ws.
// ---------------------------------------------------------------------------
__global__ __launch_bounds__(256) void cvt_kernel(
    const float* __restrict__ x,  const float* __restrict__ wq,
    const float* __restrict__ wk, const float* __restrict__ wv,
    const float* __restrict__ wo, __bf16* __restrict__ ws)
{
    const int y = blockIdx.y;
    const float* src;
    __bf16* dst;
    int n;
    if (y == 0) { src = x; dst = ws; n = XN; }
    else {
        n = WN;
        src = (y == 1) ? wq : (y == 2) ? wk : (y == 3) ? wv : wo;
        dst = ws + XN + (y - 1) * WN;
    }
    const int i = (blockIdx.x * 256 + threadIdx.x) * 4;
    if (i < n) {
        float4 f = *(const float4*)(src + i);
        bf16x4 o;
        o[0] = (__bf16)f.x; o[1] = (__bf16)f.y;
        o[2] = (__bf16)f.z; o[3] = (__bf16)f.w;
        *(bf16x4*)(dst + i) = o;
    }
}

// ---------------------------------------------------------------------------
// m97-style 128x128 GEMM core (C = A * W^T), BK=32, double-buffered LDS.
// ---------------------------------------------------------------------------
__device__ __forceinline__ void gemm128_core(
    const __bf16* __restrict__ A, const __bf16* __restrict__ W,
    int m0, int n0, __bf16* ldsA, __bf16* ldsB, floatx4 acc[4][4])
{
    const int tid  = threadIdx.x;
    const int w    = tid >> 6;
    const int lane = tid & 63;
    const int quad = lane >> 4;
    const int ln   = lane & 15;
    const int wm   = (w >> 1) << 6;
    const int wn   = (w & 1) << 6;

    const int r0c = tid >> 2, ch = tid & 3;
    const __bf16* gA0 = A + (m0 + r0c) * D_MODEL + ch * 8;
    const __bf16* gA1 = gA0 + 64 * D_MODEL;
    const __bf16* gB0 = W + (n0 + r0c) * D_MODEL + ch * 8;
    const __bf16* gB1 = gB0 + 64 * D_MODEL;
    const int lofs = w * 512;

    g2l16(gA0, ldsA + lofs);
    g2l16(gA1, ldsA + 2048 + lofs);
    g2l16(gB0, ldsB + lofs);
    g2l16(gB1, ldsB + 2048 + lofs);
    __syncthreads();

    for (int k0 = 0; k0 < D_MODEL; k0 += 32) {
        const int cur = (k0 >> 5) & 1;
        const int nxt = cur ^ 1;
        if (k0 + 32 < D_MODEL) {
            g2l16(gA0 + k0 + 32, ldsA + nxt * 4096 + lofs);
            g2l16(gA1 + k0 + 32, ldsA + nxt * 4096 + 2048 + lofs);
            g2l16(gB0 + k0 + 32, ldsB + nxt * 4096 + lofs);
            g2l16(gB1 + k0 + 32, ldsB + nxt * 4096 + 2048 + lofs);
        }
        const __bf16* cA = ldsA + cur * 4096;
        const __bf16* cB = ldsB + cur * 4096;
        bf16x8 af[4], bfr[4];
        #pragma unroll
        for (int mt = 0; mt < 4; ++mt)
            af[mt] = *(const bf16x8*)(cA + (wm + mt * 16 + ln) * 32 + quad * 8);
        #pragma unroll
        for (int nt = 0; nt < 4; ++nt)
            bfr[nt] = *(const bf16x8*)(cB + (wn + nt * 16 + ln) * 32 + quad * 8);
        #pragma unroll
        for (int mt = 0; mt < 4; ++mt)
            #pragma unroll
            for (int nt = 0; nt < 4; ++nt)
                acc[mt][nt] = MFMA(af[mt], bfr[nt], acc[mt][nt]);
        __syncthreads();
    }
}

// ---------------------------------------------------------------------------
// Kernel 1: QKV projection (C = X * W^T) + fused RoPE on Q,K.
// ---------------------------------------------------------------------------
__global__ __launch_bounds__(256) void qkv_rope_kernel(
    const __bf16* __restrict__ x,  const __bf16* __restrict__ Wq,
    const __bf16* __restrict__ Wk, const __bf16* __restrict__ Wv,
    __bf16* __restrict__ q_ws, __bf16* __restrict__ k_bf,
    __bf16* __restrict__ vT_ws,
    float* __restrict__ k_out, float* __restrict__ v_out)
{
    const int which = blockIdx.z;
    const __bf16* W = (which == 0) ? Wq : (which == 1) ? Wk : Wv;
    const int m0 = blockIdx.x * 128;
    const int n0 = blockIdx.y * 128;

    __shared__ __align__(16) __bf16 ldsA[2 * 128 * 32];
    __shared__ __align__(16) __bf16 ldsB[2 * 128 * 32];

    floatx4 acc[4][4] = {};
    gemm128_core(x, W, m0, n0, ldsA, ldsB, acc);

    const int lane = threadIdx.x & 63;
    const int w    = threadIdx.x >> 6;
    const int quad = lane >> 4;
    const int ln   = lane & 15;
    const int wm   = m0 + ((w >> 1) << 6);
    const int wn   = n0 + ((w & 1) << 6);

    #pragma unroll
    for (int nt = 0; nt < 4; ++nt) {
        const int e = wn + nt * 16 + ln;
        const int h = e >> 6;
        const int d = e & 63;
        const float invf = (which < 2)
            ? exp2f(-(float)(d & ~1) * 0.20762050593046014f) : 0.f;
        #pragma unroll
        for (int mt = 0; mt < 4; ++mt) {
            floatx4 c = acc[mt][nt];
            const int mbase = wm + mt * 16 + quad * 4;
            if (which < 2) {
                #pragma unroll
                for (int r = 0; r < 4; ++r) {
                    const int s = (mbase + r) & (SEQ - 1);
                    float self  = c[r];
                    float other = __shfl_xor(self, 1);
                    float sn, cs;
                    __sincosf((float)s * invf, &sn, &cs);
                    c[r] = (lane & 1) ? (other * sn + self * cs)
                                      : (self * cs - other * sn);
                }
            }
            const int b = mbase >> 11;
            const int s = mbase & (SEQ - 1);
            const int idx = ((b * NH + h) * SEQ + s) * HD + d;
            #pragma unroll
            for (int r = 0; r < 4; ++r) {
                if (which == 0) {
                    q_ws[idx + r * HD] = (__bf16)c[r];
                } else if (which == 1) {
                    k_out[idx + r * HD] = c[r];
                    k_bf[idx + r * HD]  = (__bf16)c[r];
                } else {
                    v_out[idx + r * HD] = c[r];
                }
            }
            if (which == 2) {
                bf16x4 pk;
                pk[0] = (__bf16)c[0]; pk[1] = (__bf16)c[1];
                pk[2] = (__bf16)c[2]; pk[3] = (__bf16)c[3];
                *(bf16x4*)(vT_ws + ((b * NH + h) * HD + d) * SEQ + s) = pk;
            }
        }
    }
}

// ---------------------------------------------------------------------------
// Kernel 2: causal flash attention, fixed-reference softmax.
// v2: K and V tiles staged ONCE per block into LDS via global_load_lds
// (double-buffered), shared by all 4 waves -> 4x less L2 traffic (was the
// bottleneck: each wave pulled its own 16KB/tile from L2 = ~8 TB/s demand).
// LDS layout XOR-swizzled (chunk ^= row&7, 16B chunks) via PRE-SWIZZLED
// global source addresses (global_load_lds writes linearly); ds_read_b128
// applies the same XOR -> conflict-free-floor reads. P-transpose buffer
// stride 64 + same XOR swizzle; total LDS = 40960 B -> 4 blocks/CU.
// ---------------------------------------------------------------------------
__global__ __launch_bounds__(256, 4) void attn_kernel(
    const __bf16* __restrict__ q_ws, const __bf16* __restrict__ k_all,
    const __bf16* __restrict__ vT,   __bf16* __restrict__ attn_ws)
{
    const int bh   = blockIdx.x & 31;
    const int qt   = 31 - (blockIdx.x >> 5);   // heavy Q-tiles dispatch first
    const int w    = threadIdx.x >> 6;
    const int lane = threadIdx.x & 63;
    const int quad = lane >> 4;
    const int ln   = lane & 15;
    const int r0   = qt * 64 + w * 16;

    const __bf16* qb = q_ws + bh * SEQ * HD;
    const __bf16* kb = k_all + bh * SEQ * HD;
    const __bf16* vb = vT + bh * HD * SEQ;

    __shared__ __align__(16) __bf16 ldsK[2][64 * 64];   // 16 KB
    __shared__ __align__(16) __bf16 ldsV[2][64 * 64];   // 16 KB
    __shared__ __align__(16) __bf16 ldsp[4][16 * 64];   //  8 KB (per-wave P)
    __bf16* lp = &ldsp[w][0];

    const bf16x8 aq0 = *(const bf16x8*)(qb + (r0 + ln) * HD + quad * 8);
    const bf16x8 aq1 = *(const bf16x8*)(qb + (r0 + ln) * HD + 32 + quad * 8);

    const int nk = qt + 1;

    // staging geometry: each wave stages rows [w*16, w*16+16) of both tiles,
    // two g2l16 calls of 8 rows each. Lane l covers (row = base + l>>3,
    // physical 16B chunk = l&7). Source fetches LOGICAL chunk (l&7)^(l>>3)
    // so that LDS physical chunk p of row r holds logical chunk p^(r&7).
    const int r8 = lane >> 3;               // 0..7
    const int cl = (lane & 7) ^ r8;         // pre-swizzled source chunk
    const int rA = w * 16 + r8;
    const int rB = rA + 8;

    // swizzled ds_read chunk offsets (elements): chunk kc*4+quad, row-xor ln&7
    const int pc0 = ((quad    ) ^ (ln & 7)) << 3;   // kc = 0
    const int pc1 = ((quad | 4) ^ (ln & 7)) << 3;   // kc = 1

    auto stage = [&](int bsel, int j0) {
        g2l16(kb + (j0 + rA) * HD + cl * 8, &ldsK[bsel][(w * 16)     * 64]);
        g2l16(kb + (j0 + rB) * HD + cl * 8, &ldsK[bsel][(w * 16 + 8) * 64]);
        g2l16(vb + rA * SEQ + j0 + cl * 8,  &ldsV[bsel][(w * 16)     * 64]);
        g2l16(vb + rB * SEQ + j0 + cl * 8,  &ldsV[bsel][(w * 16 + 8) * 64]);
    };

    floatx4 acc[4] = {};
    float l_part[4] = {0.f, 0.f, 0.f, 0.f};

    stage(0, 0);
    __syncthreads();

    for (int tk = 0; tk < nk; ++tk) {
        const int buf = tk & 1;
        if (tk + 1 < nk) stage(buf ^ 1, (tk + 1) << 6);

        const __bf16* Kb = &ldsK[buf][0];
        const __bf16* Vb = &ldsV[buf][0];
        bf16x8 K[8], V[8];
        #pragma unroll
        for (int nt = 0; nt < 4; ++nt) {
            const int rowo = (nt * 16 + ln) * 64;
            K[nt * 2 + 0] = *(const bf16x8*)(Kb + rowo + pc0);
            K[nt * 2 + 1] = *(const bf16x8*)(Kb + rowo + pc1);
            V[nt * 2 + 0] = *(const bf16x8*)(Vb + rowo + pc0);
            V[nt * 2 + 1] = *(const bf16x8*)(Vb + rowo + pc1);
        }

        floatx4 s[4] = {};
        #pragma unroll
        for (int nt = 0; nt < 4; ++nt) {
            s[nt] = MFMA(aq0, K[nt * 2 + 0], s[nt]);
            s[nt] = MFMA(aq1, K[nt * 2 + 1], s[nt]);
        }

        if (tk == nk - 1) {   // diagonal tile: causal mask
            const int j0 = tk << 6;
            #pragma unroll
            for (int nt = 0; nt < 4; ++nt) {
                const int col = j0 + nt * 16 + ln;
                #pragma unroll
                for (int r = 0; r < 4; ++r)
                    if (col > r0 + quad * 4 + r) s[nt][r] = -1e30f;
            }
        }

        floatx4 p[4];
        #pragma unroll
        for (int nt = 0; nt < 4; ++nt)
            #pragma unroll
            for (int r = 0; r < 4; ++r)
                p[nt][r] = __expf(fmaf(s[nt][r], 0.125f, -20.f));
        #pragma unroll
        for (int r = 0; r < 4; ++r)
            l_part[r] += (p[0][r] + p[1][r]) + (p[2][r] + p[3][r]);

        // P transpose through per-wave LDS, stride 64 + chunk XOR swizzle:
        // logical (row, col) stored at row*64 + ((col>>3)^(row&7))*8 + (col&7)
        #pragma unroll
        for (int nt = 0; nt < 4; ++nt) {
            const int cchunk = nt * 2 + (ln >> 3);
            #pragma unroll
            for (int r = 0; r < 4; ++r) {
                const int row = quad * 4 + r;
                lp[row * 64 + ((cchunk ^ (row & 7)) << 3) + (ln & 7)] =
                    (__bf16)p[nt][r];
            }
        }
        const bf16x8 ap0 = *(const bf16x8*)(lp + ln * 64 + pc0);
        const bf16x8 ap1 = *(const bf16x8*)(lp + ln * 64 + pc1);

        #pragma unroll
        for (int nt = 0; nt < 4; ++nt) {
            acc[nt] = MFMA(ap0, V[nt * 2 + 0], acc[nt]);
            acc[nt] = MFMA(ap1, V[nt * 2 + 1], acc[nt]);
        }
        __syncthreads();
    }

    const int b = bh >> 4, h = bh & 15;
    #pragma unroll
    for (int r = 0; r < 4; ++r) {
        float l = l_part[r];
        l += __shfl_xor(l, 1);
        l += __shfl_xor(l, 2);
        l += __shfl_xor(l, 4);
        l += __shfl_xor(l, 8);
        const float inv = 1.f / fmaxf(l, 1e-37f);
        const int s = r0 + quad * 4 + r;
        #pragma unroll
        for (int nt = 0; nt < 4; ++nt) {
            attn_ws[(b * SEQ + s) * D_MODEL + h * HD + nt * 16 + ln] =
                (__bf16)(acc[nt][r] * inv);
        }
    }
}

// ---------------------------------------------------------------------------
// Kernel 3: output projection  out = attn * Wo^T  (f32 out), m97-style core.
// ---------------------------------------------------------------------------
__global__ __launch_bounds__(256) void out_proj_kernel(
    const __bf16* __restrict__ A, const __bf16* __restrict__ Wo,
    float* __restrict__ out)
{
    const int m0 = blockIdx.x * 128;
    const int n0 = blockIdx.y * 128;

    __shared__ __align__(16) __bf16 ldsA[2 * 128 * 32];
    __shared__ __align__(16) __bf16 ldsB[2 * 128 * 32];

    floatx4 acc[4][4] = {};
    gemm128_core(A, Wo, m0, n0, ldsA, ldsB, acc);

    const int lane = threadIdx.x & 63;
    const int w    = threadIdx.x >> 6;
    const int quad = lane >> 4;
    const int ln   = lane & 15;
    const int wm   = m0 + ((w >> 1) << 6);
    const int wn   = n0 + ((w & 1) << 6);

    #pragma unroll
    for (int mt = 0; mt < 4; ++mt) {
        #pragma unroll
        for (int nt = 0; nt < 4; ++nt) {
            const floatx4 c = acc[mt][nt];
            const int e = wn + nt * 16 + ln;
            const int mbase = wm + mt * 16 + quad * 4;
            #pragma unroll
            for (int r = 0; r < 4; ++r)
                out[(mbase + r) * D_MODEL + e] = c[r];
        }
    }
}

// ---------------------------------------------------------------------------
extern "C" void kernel_launch(void* const* d_in, const int* in_sizes, int n_in,
                              void* d_out, int out_size, void* d_ws, size_t ws_size,
                              hipStream_t stream)
{
    (void)in_sizes; (void)n_in; (void)out_size; (void)ws_size;
    const float* x  = (const float*)d_in[0];
    // d_in[1] = mask — analytic causal mask, not read
    const float* Wq = (const float*)d_in[2];
    const float* Wk = (const float*)d_in[3];
    const float* Wv = (const float*)d_in[4];
    const float* Wo = (const float*)d_in[5];

    float* out   = (float*)d_out;           // [B,S,D]
    float* k_out = out + XN;                // [B,H,S,hd]
    float* v_out = k_out + XN;              // [B,H,S,hd]

    __bf16* ws      = (__bf16*)d_ws;
    __bf16* x_bf    = ws;                   // XN
    __bf16* Wq_bf   = ws + XN;              // WN
    __bf16* Wk_bf   = Wq_bf + WN;
    __bf16* Wv_bf   = Wk_bf + WN;
    __bf16* Wo_bf   = Wv_bf + WN;
    __bf16* q_ws    = Wo_bf + WN;           // XN  [B,H,S,hd]
    __bf16* k_bf    = q_ws + XN;            // XN  [B,H,S,hd]
    __bf16* vT_ws   = k_bf + XN;            // XN  [B,H,hd,S]
    __bf16* attn_ws = vT_ws + XN;           // XN  [B,S,D]

    dim3 gc(XN / 4 / 256, 5);
    cvt_kernel<<<gc, 256, 0, stream>>>(x, Wq, Wk, Wv, Wo, ws);

    dim3 g1(MROWS / 128, D_MODEL / 128, 3);
    qkv_rope_kernel<<<g1, 256, 0, stream>>>(x_bf, Wq_bf, Wk_bf, Wv_bf,
                                            q_ws, k_bf, vT_ws, k_out, v_out);

    attn_kernel<<<dim3(32 * 32), 256, 0, stream>>>(q_ws, k_bf, vT_ws, attn_ws);

    dim3 g3(MROWS / 128, D_MODEL / 128);
    out_proj_kernel<<<g3, 256, 0, stream>>>(attn_ws, Wo_bf, out);
}